// Round 3
// baseline (163.913 us; speedup 1.0000x reference)
//
#include <hip/hip_runtime.h>
#include <stdint.h>

#define BATCH   2048
#define KDIM    4096
#define NDIM    11008

#define BM 128
#define BN 256
#define BK 64
#define NT (KDIM / BK)               // 64 K-tiles
#define ABYTES (BM * BK)             // 8192
#define BBYTES (BN * BK)             // 16384
#define BUF_BYTES (ABYTES + BBYTES)  // 24576
#define A_OFF 0
#define B_OFF ABYTES

typedef __attribute__((ext_vector_type(4)))  int i32x4;
typedef __attribute__((ext_vector_type(16))) int i32x16;

typedef const __attribute__((address_space(1))) char glob_char;
typedef __attribute__((address_space(3))) char lds_char;

__device__ __forceinline__ unsigned pack4(i32x4 v) {
  return  ((unsigned)v.x & 0xFFu)
        | (((unsigned)v.y & 0xFFu) << 8)
        | (((unsigned)v.z & 0xFFu) << 16)
        | (((unsigned)v.w)         << 24);
}

__global__ __launch_bounds__(256) void convert_i32_i8(const int* __restrict__ src,
                                                      unsigned* __restrict__ dst,
                                                      int n4) {
  int idx = blockIdx.x * 256 + threadIdx.x;
  if (idx >= n4) return;
  i32x4 v = ((const i32x4*)src)[idx];
  dst[idx] = pack4(v);
}

// C[2048][11008] = A[2048][4096] * W[11008][4096]^T via mfma_i32_32x32x32_i8.
// 128x256 block tile, 4 waves (2m x 2n), per-wave 64x128 (2x4 frags of 32x32),
// BK=64 (2 k-subs per tile). 3 rotating LDS buffers, 2-tile prefetch,
// counted s_waitcnt vmcnt(6) once per K-tile, raw s_barrier, 2 phases per
// K-tile each = {stage 3 gloads || ds_read next frags -> barrier -> 8 MFMA}.
// Slot swizzle (r0-validated, 0 conflicts): within each 64B row, physical
// 16B slot p holds logical slot p ^ ((row>>1)&3); applied on the global
// SOURCE for global_load_lds (linear dest) and on the ds_read address.
__global__ __launch_bounds__(256, 2) void ternary_gemm(const char* __restrict__ A8,
                                                       const char* __restrict__ B8,
                                                       const float* __restrict__ scale,
                                                       const float* __restrict__ bias,
                                                       float* __restrict__ out) {
  __shared__ char lds[3 * BUF_BYTES];

  const int tid  = threadIdx.x;
  const int wid  = tid >> 6;
  const int lane = tid & 63;
  const int l31  = lane & 31;
  const int lhi  = lane >> 5;

  // XCD-aware swizzle; gridDim.x = 688, 688 % 8 == 0 -> bijective
  const int nwg = gridDim.x;
  const int cpx = nwg >> 3;
  const int wg  = (blockIdx.x & 7) * cpx + (blockIdx.x >> 3);
  const int mt = wg & 15;            // 16 M-tiles; consecutive wg share N-panel
  const int nt = wg >> 4;            // 43 N-tiles
  const int arow0 = mt * BM;
  const int brow0 = nt * BN;

  const int wr = wid >> 1;           // 0..1 : 64-row group
  const int wc = wid & 1;            // 0..1 : 128-col group

  // staging geometry: round = 4KB = 256 thr x 16B; A rounds 0-1, B rounds 0-3
  const int srow = tid >> 2;
  const int sslot = tid & 3;

  auto stageA = [&](char* base, int kt, int r) {
    const int row = r * 64 + srow;
    const int sl  = sslot ^ ((row >> 1) & 3);
    __builtin_amdgcn_global_load_lds(
        (glob_char*)(A8 + (size_t)(arow0 + row) * KDIM + kt * BK + sl * 16),
        (lds_char*)(base + A_OFF + r * 4096 + wid * 1024), 16, 0, 0);
  };
  auto stageB = [&](char* base, int kt, int r) {
    const int row = r * 64 + srow;
    const int sl  = sslot ^ ((row >> 1) & 3);
    __builtin_amdgcn_global_load_lds(
        (glob_char*)(B8 + (size_t)(brow0 + row) * KDIM + kt * BK + sl * 16),
        (lds_char*)(base + B_OFF + r * 4096 + wid * 1024), 16, 0, 0);
  };

  // loop-invariant fragment byte-offsets within a buffer
  int offA[2][2], offB[4][2];
#pragma unroll
  for (int m = 0; m < 2; ++m)
#pragma unroll
    for (int kk = 0; kk < 2; ++kk) {
      const int row = wr * 64 + m * 32 + l31;
      const int p   = (kk * 2 + lhi) ^ ((row >> 1) & 3);
      offA[m][kk] = A_OFF + row * 64 + p * 16;
    }
#pragma unroll
  for (int n = 0; n < 4; ++n)
#pragma unroll
    for (int kk = 0; kk < 2; ++kk) {
      const int row = wc * 128 + n * 32 + l31;
      const int p   = (kk * 2 + lhi) ^ ((row >> 1) & 3);
      offB[n][kk] = B_OFF + row * 64 + p * 16;
    }

  i32x16 acc[2][4];
#pragma unroll
  for (int m = 0; m < 2; ++m)
#pragma unroll
    for (int n = 0; n < 4; ++n)
      acc[m][n] = (i32x16)(0);

  char* b0 = lds;
  char* b1 = lds + BUF_BYTES;
  char* b2 = lds + 2 * BUF_BYTES;

  // prologue: stage tiles 0 and 1; wait tile 0 (6 oldest) only
  stageA(b0, 0, 0); stageA(b0, 0, 1);
  stageB(b0, 0, 0); stageB(b0, 0, 1); stageB(b0, 0, 2); stageB(b0, 0, 3);
  stageA(b1, 1, 0); stageA(b1, 1, 1);
  stageB(b1, 1, 0); stageB(b1, 1, 1); stageB(b1, 1, 2); stageB(b1, 1, 3);
  asm volatile("s_waitcnt vmcnt(6)" ::: "memory");
  __builtin_amdgcn_s_barrier();

  i32x4 fa0[2], fb0[4], fa1[2], fb1[4];
#pragma unroll
  for (int m = 0; m < 2; ++m) fa0[m] = *(const i32x4*)(b0 + offA[m][0]);
#pragma unroll
  for (int n = 0; n < 4; ++n) fb0[n] = *(const i32x4*)(b0 + offB[n][0]);

  for (int t = 0; t < NT; ++t) {
    const int kt2 = (t + 2 <= NT - 1) ? t + 2 : NT - 1;  // clamped dummy at tail

    // ---- PHASE A: stage 3 || read k1 frags -> barrier -> MFMA k0 ----
    stageA(b2, kt2, 0);
    stageA(b2, kt2, 1);
    stageB(b2, kt2, 0);
#pragma unroll
    for (int m = 0; m < 2; ++m) fa1[m] = *(const i32x4*)(b0 + offA[m][1]);
#pragma unroll
    for (int n = 0; n < 4; ++n) fb1[n] = *(const i32x4*)(b0 + offB[n][1]);
    __builtin_amdgcn_s_barrier();

    __builtin_amdgcn_s_setprio(1);
#pragma unroll
    for (int m = 0; m < 2; ++m)
#pragma unroll
      for (int n = 0; n < 4; ++n)
        acc[m][n] = __builtin_amdgcn_mfma_i32_32x32x32_i8(fa0[m], fb0[n], acc[m][n], 0, 0, 0);
    __builtin_amdgcn_s_setprio(0);

    // ---- PHASE B: stage 3 -> vmcnt(6) (tile t+1 landed) -> barrier ->
    //              read (t+1,k0) frags -> MFMA k1 -> barrier ----
    stageB(b2, kt2, 1);
    stageB(b2, kt2, 2);
    stageB(b2, kt2, 3);
    asm volatile("s_waitcnt vmcnt(6)" ::: "memory");
    __builtin_amdgcn_s_barrier();

    if (t < NT - 1) {
#pragma unroll
      for (int m = 0; m < 2; ++m) fa0[m] = *(const i32x4*)(b1 + offA[m][0]);
#pragma unroll
      for (int n = 0; n < 4; ++n) fb0[n] = *(const i32x4*)(b1 + offB[n][0]);
    }

    __builtin_amdgcn_s_setprio(1);
#pragma unroll
    for (int m = 0; m < 2; ++m)
#pragma unroll
      for (int n = 0; n < 4; ++n)
        acc[m][n] = __builtin_amdgcn_mfma_i32_32x32x32_i8(fa1[m], fb1[n], acc[m][n], 0, 0, 0);
    __builtin_amdgcn_s_setprio(0);
    __builtin_amdgcn_s_barrier();   // all waves' b0-reads retired before b0 is re-staged

    char* tb = b0; b0 = b1; b1 = b2; b2 = tb;
    __builtin_amdgcn_sched_barrier(0);
  }

  // Epilogue: 32x32 C/D layout (m74/m101): col = lane&31,
  // row = (reg&3) + 8*(reg>>2) + 4*(lane>>5)
#pragma unroll
  for (int n = 0; n < 4; ++n) {
    const int col = brow0 + wc * 128 + n * 32 + l31;
    const float sc = scale[col];
    const float bs = bias[col];
#pragma unroll
    for (int m = 0; m < 2; ++m) {
      const int r0 = arow0 + wr * 64 + m * 32 + 4 * lhi;
#pragma unroll
      for (int reg = 0; reg < 16; ++reg) {
        const int row = r0 + (reg & 3) + 8 * (reg >> 2);
        out[(size_t)row * NDIM + col] = (float)acc[m][n][reg] * sc + bs;
      }
    }
  }
}

extern "C" void kernel_launch(void* const* d_in, const int* in_sizes, int n_in,
                              void* d_out, int out_size, void* d_ws, size_t ws_size,
                              hipStream_t stream) {
  const int*   input  = (const int*)d_in[0];     // [2048][4096] int32
  const int*   weight = (const int*)d_in[1];     // [11008][4096] int32 in {-1,0,1}
  const float* scale  = (const float*)d_in[2];   // [11008]
  const float* bias   = (const float*)d_in[3];   // [11008]
  float*       out    = (float*)d_out;           // [2048][11008] fp32

  const size_t needA = (size_t)BATCH * KDIM;     // 8 MB int8
  const size_t needB = (size_t)NDIM * KDIM;      // 44 MB int8

  char* A8 = (char*)d_ws;
  char* B8 = A8 + needA;
  const int nA4 = (int)(needA / 4);
  const int nB4 = (int)(needB / 4);
  convert_i32_i8<<<(nA4 + 255) / 256, 256, 0, stream>>>(input, (unsigned*)A8, nA4);
  convert_i32_i8<<<(nB4 + 255) / 256, 256, 0, stream>>>(weight, (unsigned*)B8, nB4);

  const dim3 grid((BATCH / BM) * (NDIM / BN));   // 16 * 43 = 688
  const dim3 block(256);
  ternary_gemm<<<grid, block, 0, stream>>>(A8, B8, scale, bias, out);
  (void)ws_size; (void)n_in; (void)in_sizes; (void)out_size;
}

// Round 4
// 156.169 us; speedup vs baseline: 1.0496x; 1.0496x over previous
//
#include <hip/hip_runtime.h>
#include <stdint.h>

#define BATCH   2048
#define KDIM    4096
#define NDIM    11008

#define BM 128
#define BN 256
#define BK 64
#define NT (KDIM / BK)               // 64 K-tiles
#define ABYTES (BM * BK)             // 8192
#define BBYTES (BN * BK)             // 16384
#define BUF_BYTES (ABYTES + BBYTES)  // 24576
#define A_OFF 0
#define B_OFF ABYTES

typedef __attribute__((ext_vector_type(4))) int i32x4;

typedef const __attribute__((address_space(1))) char glob_char;
typedef __attribute__((address_space(3))) char lds_char;

__device__ __forceinline__ unsigned pack4(i32x4 v) {
  return  ((unsigned)v.x & 0xFFu)
        | (((unsigned)v.y & 0xFFu) << 8)
        | (((unsigned)v.z & 0xFFu) << 16)
        | (((unsigned)v.w)         << 24);
}

__global__ __launch_bounds__(256) void convert_i32_i8(const int* __restrict__ src,
                                                      unsigned* __restrict__ dst,
                                                      int n4) {
  int idx = blockIdx.x * 256 + threadIdx.x;
  if (idx >= n4) return;
  i32x4 v = ((const i32x4*)src)[idx];
  dst[idx] = pack4(v);
}

// C[2048][11008] = A[2048][4096] * W[11008][4096]^T via mfma_i32_16x16x64_i8.
// 128x256 tile, 8 waves (2m x 4n), per-wave 64x64 as 4x4 frags of 16x16x64.
// 8-phase-style schedule: per K-tile 4 phases, each =
//   {ds_read this phase's frags || issue 1 staging gload -> s_barrier ->
//    setprio(1) + 4-MFMA quadrant + setprio(0) -> s_barrier},
// quadrants snaked (Q0=aL*bL, Q1=aL*bH, Q2=aH*bH, Q3=aH*bL).
// 3 rotating LDS buffers, depth-2 prefetch, ONE counted vmcnt(3) per K-tile
// (phase 3, after all 3 prefetch issues; barrier after it makes the retire
// visible cross-wave before any read of the t+1 buffer).
// Slot swizzle (R0/R2-validated, 0 conflicts): within each 64B row, physical
// 16B slot p holds logical slot p ^ ((row>>1)&3); applied on the global
// SOURCE for global_load_lds (linear dest) and on the ds_read address.
__global__ __launch_bounds__(512, 4) void ternary_gemm(const char* __restrict__ A8,
                                                       const char* __restrict__ B8,
                                                       const float* __restrict__ scale,
                                                       const float* __restrict__ bias,
                                                       float* __restrict__ out) {
  __shared__ char lds[3 * BUF_BYTES];

  const int tid  = threadIdx.x;
  const int wid  = tid >> 6;
  const int lane = tid & 63;

  // XCD-aware swizzle; gridDim.x = 688, 688 % 8 == 0 -> bijective
  const int nwg = gridDim.x;
  const int cpx = nwg >> 3;
  const int wg  = (blockIdx.x & 7) * cpx + (blockIdx.x >> 3);
  const int mt = wg & 15;            // consecutive wg share the N-panel
  const int nt = wg >> 4;
  const int arow0 = mt * BM;
  const int brow0 = nt * BN;

  const int wr = wid >> 2;           // 0..1 : 64-row half
  const int wc = wid & 3;            // 0..3 : 64-col quarter
  const int rsub = lane & 15;
  const int sgrp = lane >> 4;        // k-slot 0..3

  // staging geometry: 512 thr x 16B = 8KB/round; A: 1 round, B: 2 rounds
  const int srow  = tid >> 2;        // 0..127
  const int sslot = (tid & 3) ^ ((srow >> 1) & 3);
  const char* gA  = A8 + (size_t)(arow0 + srow) * KDIM + sslot * 16;
  const char* gB0 = B8 + (size_t)(brow0 + srow) * KDIM + sslot * 16;
  const char* gB1 = B8 + (size_t)(brow0 + 128 + srow) * KDIM + sslot * 16; // (128+srow)>>1&3 == (srow>>1)&3

  auto stageA = [&](int bufo, int kt) {
    __builtin_amdgcn_global_load_lds((glob_char*)(gA + kt * BK),
        (lds_char*)(lds + bufo + A_OFF + wid * 1024), 16, 0, 0);
  };
  auto stageB = [&](int bufo, int kt, int r) {
    const char* g = (r == 0) ? gB0 : gB1;
    __builtin_amdgcn_global_load_lds((glob_char*)(g + kt * BK),
        (lds_char*)(lds + bufo + B_OFF + r * 8192 + wid * 1024), 16, 0, 0);
  };

  // loop-invariant fragment byte-offsets within a buffer (0-conflict pattern)
  int offA[4], offB[4];
#pragma unroll
  for (int m = 0; m < 4; ++m) {
    const int row = wr * 64 + m * 16 + rsub;
    const int p   = sgrp ^ ((row >> 1) & 3);
    offA[m] = A_OFF + row * 64 + p * 16;
  }
#pragma unroll
  for (int n = 0; n < 4; ++n) {
    const int row = wc * 64 + n * 16 + rsub;
    const int p   = sgrp ^ ((row >> 1) & 3);
    offB[n] = B_OFF + row * 64 + p * 16;
  }

  i32x4 acc[4][4];
#pragma unroll
  for (int m = 0; m < 4; ++m)
#pragma unroll
    for (int n = 0; n < 4; ++n)
      acc[m][n] = (i32x4){0, 0, 0, 0};

  int cur = 0, nxt = BUF_BYTES, pf = 2 * BUF_BYTES;

  // prologue: stage tiles 0 and 1 (issue order B0,B1,A per tile, matching loop)
  stageB(cur, 0, 0); stageB(cur, 0, 1); stageA(cur, 0);
  stageB(nxt, 1, 0); stageB(nxt, 1, 1); stageA(nxt, 1);
  asm volatile("s_waitcnt vmcnt(3)" ::: "memory");   // tile 0 landed
  __builtin_amdgcn_s_barrier();

  for (int t = 0; t < NT; ++t) {
    const int kt2 = (t + 2 < NT) ? t + 2 : NT - 1;   // clamped dummy at tail

    i32x4 a0, a1, a2, a3, b0, b1, b2, b3;

    // ---- P0: read aL,bL ; stage B r0 ; Q0 = aL x bL ----
    a0 = *(const i32x4*)(lds + cur + offA[0]);
    a1 = *(const i32x4*)(lds + cur + offA[1]);
    b0 = *(const i32x4*)(lds + cur + offB[0]);
    b1 = *(const i32x4*)(lds + cur + offB[1]);
    stageB(pf, kt2, 0);
    __builtin_amdgcn_s_barrier();
    __builtin_amdgcn_s_setprio(1);
    acc[0][0] = __builtin_amdgcn_mfma_i32_16x16x64_i8(a0, b0, acc[0][0], 0, 0, 0);
    acc[0][1] = __builtin_amdgcn_mfma_i32_16x16x64_i8(a0, b1, acc[0][1], 0, 0, 0);
    acc[1][0] = __builtin_amdgcn_mfma_i32_16x16x64_i8(a1, b0, acc[1][0], 0, 0, 0);
    acc[1][1] = __builtin_amdgcn_mfma_i32_16x16x64_i8(a1, b1, acc[1][1], 0, 0, 0);
    __builtin_amdgcn_s_setprio(0);
    __builtin_amdgcn_s_barrier();

    // ---- P1: read bH ; stage B r1 ; Q1 = aL x bH ----
    b2 = *(const i32x4*)(lds + cur + offB[2]);
    b3 = *(const i32x4*)(lds + cur + offB[3]);
    stageB(pf, kt2, 1);
    __builtin_amdgcn_s_barrier();
    __builtin_amdgcn_s_setprio(1);
    acc[0][2] = __builtin_amdgcn_mfma_i32_16x16x64_i8(a0, b2, acc[0][2], 0, 0, 0);
    acc[0][3] = __builtin_amdgcn_mfma_i32_16x16x64_i8(a0, b3, acc[0][3], 0, 0, 0);
    acc[1][2] = __builtin_amdgcn_mfma_i32_16x16x64_i8(a1, b2, acc[1][2], 0, 0, 0);
    acc[1][3] = __builtin_amdgcn_mfma_i32_16x16x64_i8(a1, b3, acc[1][3], 0, 0, 0);
    __builtin_amdgcn_s_setprio(0);
    __builtin_amdgcn_s_barrier();

    // ---- P2: read aH ; stage A ; Q2 = aH x bH ----
    a2 = *(const i32x4*)(lds + cur + offA[2]);
    a3 = *(const i32x4*)(lds + cur + offA[3]);
    stageA(pf, kt2);
    __builtin_amdgcn_s_barrier();
    __builtin_amdgcn_s_setprio(1);
    acc[2][2] = __builtin_amdgcn_mfma_i32_16x16x64_i8(a2, b2, acc[2][2], 0, 0, 0);
    acc[2][3] = __builtin_amdgcn_mfma_i32_16x16x64_i8(a2, b3, acc[2][3], 0, 0, 0);
    acc[3][2] = __builtin_amdgcn_mfma_i32_16x16x64_i8(a3, b2, acc[3][2], 0, 0, 0);
    acc[3][3] = __builtin_amdgcn_mfma_i32_16x16x64_i8(a3, b3, acc[3][3], 0, 0, 0);
    __builtin_amdgcn_s_setprio(0);
    __builtin_amdgcn_s_barrier();

    // ---- P3: vmcnt(3) retires tile t+1's 3 loads (t+2's 3 stay in flight);
    //          barrier makes that visible to all waves; Q3 = aH x bL ----
    asm volatile("s_waitcnt vmcnt(3)" ::: "memory");
    __builtin_amdgcn_s_barrier();
    __builtin_amdgcn_s_setprio(1);
    acc[2][0] = __builtin_amdgcn_mfma_i32_16x16x64_i8(a2, b0, acc[2][0], 0, 0, 0);
    acc[2][1] = __builtin_amdgcn_mfma_i32_16x16x64_i8(a2, b1, acc[2][1], 0, 0, 0);
    acc[3][0] = __builtin_amdgcn_mfma_i32_16x16x64_i8(a3, b0, acc[3][0], 0, 0, 0);
    acc[3][1] = __builtin_amdgcn_mfma_i32_16x16x64_i8(a3, b1, acc[3][1], 0, 0, 0);
    __builtin_amdgcn_s_setprio(0);
    __builtin_amdgcn_s_barrier();

    const int tb = cur; cur = nxt; nxt = pf; pf = tb;
  }

  // Epilogue (R1/R2-validated): C/D col = lane&15, row = (lane>>4)*4 + reg
  const int crow = sgrp * 4;
#pragma unroll
  for (int n = 0; n < 4; ++n) {
    const int col = brow0 + wc * 64 + n * 16 + rsub;
    const float sc = scale[col];
    const float bs = bias[col];
#pragma unroll
    for (int m = 0; m < 4; ++m) {
      const int r0 = arow0 + wr * 64 + m * 16 + crow;
#pragma unroll
      for (int j = 0; j < 4; ++j) {
        out[(size_t)(r0 + j) * NDIM + col] = (float)acc[m][n][j] * sc + bs;
      }
    }
  }
}

extern "C" void kernel_launch(void* const* d_in, const int* in_sizes, int n_in,
                              void* d_out, int out_size, void* d_ws, size_t ws_size,
                              hipStream_t stream) {
  const int*   input  = (const int*)d_in[0];     // [2048][4096] int32
  const int*   weight = (const int*)d_in[1];     // [11008][4096] int32 in {-1,0,1}
  const float* scale  = (const float*)d_in[2];   // [11008]
  const float* bias   = (const float*)d_in[3];   // [11008]
  float*       out    = (float*)d_out;           // [2048][11008] fp32

  const size_t needA = (size_t)BATCH * KDIM;     // 8 MB int8
  const size_t needB = (size_t)NDIM * KDIM;      // 44 MB int8

  char* A8 = (char*)d_ws;
  char* B8 = A8 + needA;
  const int nA4 = (int)(needA / 4);
  const int nB4 = (int)(needB / 4);
  convert_i32_i8<<<(nA4 + 255) / 256, 256, 0, stream>>>(input, (unsigned*)A8, nA4);
  convert_i32_i8<<<(nB4 + 255) / 256, 256, 0, stream>>>(weight, (unsigned*)B8, nB4);

  const dim3 grid((BATCH / BM) * (NDIM / BN));   // 16 * 43 = 688
  const dim3 block(512);
  ternary_gemm<<<grid, block, 0, stream>>>(A8, B8, scale, bias, out);
  (void)ws_size; (void)n_in; (void)in_sizes; (void)out_size;
}

// Round 5
// 155.418 us; speedup vs baseline: 1.0547x; 1.0048x over previous
//
#include <hip/hip_runtime.h>
#include <stdint.h>

#define BATCH   2048
#define KDIM    4096
#define NDIM    11008

#define BM 128
#define BN 256
#define BK 64
#define NT (KDIM / BK)               // 64 K-tiles
#define ABYTES (BM * BK)             // 8192
#define BBYTES (BN * BK)             // 16384
#define BUF_BYTES (ABYTES + BBYTES)  // 24576
#define A_OFF 0
#define B_OFF ABYTES

typedef __attribute__((ext_vector_type(4))) int i32x4;

typedef const __attribute__((address_space(1))) char glob_char;
typedef __attribute__((address_space(3))) char lds_char;

__device__ __forceinline__ unsigned pack4(i32x4 v) {
  return  ((unsigned)v.x & 0xFFu)
        | (((unsigned)v.y & 0xFFu) << 8)
        | (((unsigned)v.z & 0xFFu) << 16)
        | (((unsigned)v.w)         << 24);
}

__global__ __launch_bounds__(256) void convert_i32_i8(const int* __restrict__ src,
                                                      unsigned* __restrict__ dst,
                                                      int n4) {
  int idx = blockIdx.x * 256 + threadIdx.x;
  if (idx >= n4) return;
  i32x4 v = ((const i32x4*)src)[idx];
  dst[idx] = pack4(v);
}

// C[2048][11008] = A[2048][4096] * W[11008][4096]^T via mfma_i32_16x16x64_i8.
// 128x256 tile, 4 waves (2m x 2n), per-wave 64x128 as 4x8 frags (32 MFMA/KT)
// -> LDS-read intensity halved vs the 64x64 wave-tile (11.4 B/Kop vs 16).
// Per K-tile 4 phases x 8 MFMA:
//   P0: read a01,b0123 (6 ds) ; stage B r0,r1 ; bar ; A01 x B0123 ; bar
//   P1: read b4567 (4 ds)     ; stage B r2,r3 ; bar ; A01 x B4567 ; bar
//   P2: read a23 (2 ds)       ; stage A r0,r1 ; bar ; A23 x B4567 ; bar
//   P3: vmcnt(6) (tile t+1 landed; t+2's 6 in flight) ; bar ; A23 x B0123 ; bar
// 3 rotating LDS buffers, depth-2 prefetch, counted vmcnt only (never 0).
// Slot swizzle (R0/R2/R4-validated, 0 conflicts): within each 64B row,
// physical 16B slot p holds logical slot p ^ ((row>>1)&3); applied on the
// global SOURCE for global_load_lds (linear dest) and on the ds_read addr.
__global__ __launch_bounds__(256, 2) void ternary_gemm(const char* __restrict__ A8,
                                                       const char* __restrict__ B8,
                                                       const float* __restrict__ scale,
                                                       const float* __restrict__ bias,
                                                       float* __restrict__ out) {
  __shared__ char lds[3 * BUF_BYTES];

  const int tid  = threadIdx.x;
  const int wid  = tid >> 6;
  const int lane = tid & 63;

  // XCD-aware swizzle; gridDim.x = 688, 688 % 8 == 0 -> bijective
  const int nwg = gridDim.x;
  const int cpx = nwg >> 3;
  const int wg  = (blockIdx.x & 7) * cpx + (blockIdx.x >> 3);
  const int mt = wg & 15;            // consecutive wg share the N-panel
  const int nt = wg >> 4;
  const int arow0 = mt * BM;
  const int brow0 = nt * BN;

  const int wr = wid >> 1;           // 0..1 : 64-row half
  const int wc = wid & 1;            // 0..1 : 128-col half
  const int rsub = lane & 15;
  const int sgrp = lane >> 4;        // k-slot 0..3

  // staging: 256 thr x 16B = 4KB/round = 64 rows; A rounds 0-1, B rounds 0-3
  const int srow  = tid >> 2;        // 0..63
  const int sslot = (tid & 3) ^ ((srow >> 1) & 3);   // r*64 doesn't touch row bits 1-2
  const char* gA0 = A8 + (size_t)(arow0       + srow) * KDIM + sslot * 16;
  const char* gA1 = A8 + (size_t)(arow0 +  64 + srow) * KDIM + sslot * 16;
  const char* gB0 = B8 + (size_t)(brow0       + srow) * KDIM + sslot * 16;
  const char* gB1 = B8 + (size_t)(brow0 +  64 + srow) * KDIM + sslot * 16;
  const char* gB2 = B8 + (size_t)(brow0 + 128 + srow) * KDIM + sslot * 16;
  const char* gB3 = B8 + (size_t)(brow0 + 192 + srow) * KDIM + sslot * 16;

  auto stage = [&](const char* g, int bufo, int kt, int dsto) {
    __builtin_amdgcn_global_load_lds((glob_char*)(g + kt * BK),
        (lds_char*)(lds + bufo + dsto + wid * 1024), 16, 0, 0);
  };

  // loop-invariant fragment byte-offsets (0-conflict pattern)
  int offA[4], offB[8];
#pragma unroll
  for (int m = 0; m < 4; ++m) {
    const int row = wr * 64 + m * 16 + rsub;
    const int p   = sgrp ^ ((row >> 1) & 3);
    offA[m] = A_OFF + row * 64 + p * 16;
  }
#pragma unroll
  for (int n = 0; n < 8; ++n) {
    const int row = wc * 128 + n * 16 + rsub;
    const int p   = sgrp ^ ((row >> 1) & 3);
    offB[n] = B_OFF + row * 64 + p * 16;
  }

  i32x4 acc[4][8];
#pragma unroll
  for (int m = 0; m < 4; ++m)
#pragma unroll
    for (int n = 0; n < 8; ++n)
      acc[m][n] = (i32x4){0, 0, 0, 0};

  int cur = 0, nxt = BUF_BYTES, pf = 2 * BUF_BYTES;

  // prologue: stage tiles 0 and 1 in loop issue order (B0,B1,B2,B3,A0,A1)
  stage(gB0, cur, 0, B_OFF);         stage(gB1, cur, 0, B_OFF + 4096);
  stage(gB2, cur, 0, B_OFF + 8192);  stage(gB3, cur, 0, B_OFF + 12288);
  stage(gA0, cur, 0, A_OFF);         stage(gA1, cur, 0, A_OFF + 4096);
  stage(gB0, nxt, 1, B_OFF);         stage(gB1, nxt, 1, B_OFF + 4096);
  stage(gB2, nxt, 1, B_OFF + 8192);  stage(gB3, nxt, 1, B_OFF + 12288);
  stage(gA0, nxt, 1, A_OFF);         stage(gA1, nxt, 1, A_OFF + 4096);
  asm volatile("s_waitcnt vmcnt(6)" ::: "memory");   // tile 0 landed
  __builtin_amdgcn_s_barrier();

  for (int t = 0; t < NT; ++t) {
    const int kt2 = (t + 2 < NT) ? t + 2 : NT - 1;   // clamped dummy at tail

    i32x4 a0, a1, a2, a3, b0, b1, b2, b3, b4, b5, b6, b7;

    // ---- P0: read a01,b0123 ; stage B r0,r1 ; A01 x B0123 ----
    a0 = *(const i32x4*)(lds + cur + offA[0]);
    a1 = *(const i32x4*)(lds + cur + offA[1]);
    b0 = *(const i32x4*)(lds + cur + offB[0]);
    b1 = *(const i32x4*)(lds + cur + offB[1]);
    b2 = *(const i32x4*)(lds + cur + offB[2]);
    b3 = *(const i32x4*)(lds + cur + offB[3]);
    stage(gB0, pf, kt2, B_OFF);
    stage(gB1, pf, kt2, B_OFF + 4096);
    __builtin_amdgcn_s_barrier();
    __builtin_amdgcn_s_setprio(1);
    acc[0][0] = __builtin_amdgcn_mfma_i32_16x16x64_i8(a0, b0, acc[0][0], 0, 0, 0);
    acc[0][1] = __builtin_amdgcn_mfma_i32_16x16x64_i8(a0, b1, acc[0][1], 0, 0, 0);
    acc[0][2] = __builtin_amdgcn_mfma_i32_16x16x64_i8(a0, b2, acc[0][2], 0, 0, 0);
    acc[0][3] = __builtin_amdgcn_mfma_i32_16x16x64_i8(a0, b3, acc[0][3], 0, 0, 0);
    acc[1][0] = __builtin_amdgcn_mfma_i32_16x16x64_i8(a1, b0, acc[1][0], 0, 0, 0);
    acc[1][1] = __builtin_amdgcn_mfma_i32_16x16x64_i8(a1, b1, acc[1][1], 0, 0, 0);
    acc[1][2] = __builtin_amdgcn_mfma_i32_16x16x64_i8(a1, b2, acc[1][2], 0, 0, 0);
    acc[1][3] = __builtin_amdgcn_mfma_i32_16x16x64_i8(a1, b3, acc[1][3], 0, 0, 0);
    __builtin_amdgcn_s_setprio(0);
    __builtin_amdgcn_s_barrier();

    // ---- P1: read b4567 ; stage B r2,r3 ; A01 x B4567 ----
    b4 = *(const i32x4*)(lds + cur + offB[4]);
    b5 = *(const i32x4*)(lds + cur + offB[5]);
    b6 = *(const i32x4*)(lds + cur + offB[6]);
    b7 = *(const i32x4*)(lds + cur + offB[7]);
    stage(gB2, pf, kt2, B_OFF + 8192);
    stage(gB3, pf, kt2, B_OFF + 12288);
    __builtin_amdgcn_s_barrier();
    __builtin_amdgcn_s_setprio(1);
    acc[0][4] = __builtin_amdgcn_mfma_i32_16x16x64_i8(a0, b4, acc[0][4], 0, 0, 0);
    acc[0][5] = __builtin_amdgcn_mfma_i32_16x16x64_i8(a0, b5, acc[0][5], 0, 0, 0);
    acc[0][6] = __builtin_amdgcn_mfma_i32_16x16x64_i8(a0, b6, acc[0][6], 0, 0, 0);
    acc[0][7] = __builtin_amdgcn_mfma_i32_16x16x64_i8(a0, b7, acc[0][7], 0, 0, 0);
    acc[1][4] = __builtin_amdgcn_mfma_i32_16x16x64_i8(a1, b4, acc[1][4], 0, 0, 0);
    acc[1][5] = __builtin_amdgcn_mfma_i32_16x16x64_i8(a1, b5, acc[1][5], 0, 0, 0);
    acc[1][6] = __builtin_amdgcn_mfma_i32_16x16x64_i8(a1, b6, acc[1][6], 0, 0, 0);
    acc[1][7] = __builtin_amdgcn_mfma_i32_16x16x64_i8(a1, b7, acc[1][7], 0, 0, 0);
    __builtin_amdgcn_s_setprio(0);
    __builtin_amdgcn_s_barrier();

    // ---- P2: read a23 ; stage A r0,r1 ; A23 x B4567 ----
    a2 = *(const i32x4*)(lds + cur + offA[2]);
    a3 = *(const i32x4*)(lds + cur + offA[3]);
    stage(gA0, pf, kt2, A_OFF);
    stage(gA1, pf, kt2, A_OFF + 4096);
    __builtin_amdgcn_s_barrier();
    __builtin_amdgcn_s_setprio(1);
    acc[2][4] = __builtin_amdgcn_mfma_i32_16x16x64_i8(a2, b4, acc[2][4], 0, 0, 0);
    acc[2][5] = __builtin_amdgcn_mfma_i32_16x16x64_i8(a2, b5, acc[2][5], 0, 0, 0);
    acc[2][6] = __builtin_amdgcn_mfma_i32_16x16x64_i8(a2, b6, acc[2][6], 0, 0, 0);
    acc[2][7] = __builtin_amdgcn_mfma_i32_16x16x64_i8(a2, b7, acc[2][7], 0, 0, 0);
    acc[3][4] = __builtin_amdgcn_mfma_i32_16x16x64_i8(a3, b4, acc[3][4], 0, 0, 0);
    acc[3][5] = __builtin_amdgcn_mfma_i32_16x16x64_i8(a3, b5, acc[3][5], 0, 0, 0);
    acc[3][6] = __builtin_amdgcn_mfma_i32_16x16x64_i8(a3, b6, acc[3][6], 0, 0, 0);
    acc[3][7] = __builtin_amdgcn_mfma_i32_16x16x64_i8(a3, b7, acc[3][7], 0, 0, 0);
    __builtin_amdgcn_s_setprio(0);
    __builtin_amdgcn_s_barrier();

    // ---- P3: t+1's 6 loads retire (t+2's 6 stay in flight) ; A23 x B0123 ----
    asm volatile("s_waitcnt vmcnt(6)" ::: "memory");
    __builtin_amdgcn_s_barrier();
    __builtin_amdgcn_s_setprio(1);
    acc[2][0] = __builtin_amdgcn_mfma_i32_16x16x64_i8(a2, b0, acc[2][0], 0, 0, 0);
    acc[2][1] = __builtin_amdgcn_mfma_i32_16x16x64_i8(a2, b1, acc[2][1], 0, 0, 0);
    acc[2][2] = __builtin_amdgcn_mfma_i32_16x16x64_i8(a2, b2, acc[2][2], 0, 0, 0);
    acc[2][3] = __builtin_amdgcn_mfma_i32_16x16x64_i8(a2, b3, acc[2][3], 0, 0, 0);
    acc[3][0] = __builtin_amdgcn_mfma_i32_16x16x64_i8(a3, b0, acc[3][0], 0, 0, 0);
    acc[3][1] = __builtin_amdgcn_mfma_i32_16x16x64_i8(a3, b1, acc[3][1], 0, 0, 0);
    acc[3][2] = __builtin_amdgcn_mfma_i32_16x16x64_i8(a3, b2, acc[3][2], 0, 0, 0);
    acc[3][3] = __builtin_amdgcn_mfma_i32_16x16x64_i8(a3, b3, acc[3][3], 0, 0, 0);
    __builtin_amdgcn_s_setprio(0);
    __builtin_amdgcn_s_barrier();

    const int tb = cur; cur = nxt; nxt = pf; pf = tb;
  }

  // Epilogue (validated): C/D col = lane&15, row = (lane>>4)*4 + reg
  const int crow = sgrp * 4;
#pragma unroll
  for (int n = 0; n < 8; ++n) {
    const int col = brow0 + wc * 128 + n * 16 + rsub;
    const float sc = scale[col];
    const float bs = bias[col];
#pragma unroll
    for (int m = 0; m < 4; ++m) {
      const int r0 = arow0 + wr * 64 + m * 16 + crow;
#pragma unroll
      for (int j = 0; j < 4; ++j) {
        out[(size_t)(r0 + j) * NDIM + col] = (float)acc[m][n][j] * sc + bs;
      }
    }
  }
}

extern "C" void kernel_launch(void* const* d_in, const int* in_sizes, int n_in,
                              void* d_out, int out_size, void* d_ws, size_t ws_size,
                              hipStream_t stream) {
  const int*   input  = (const int*)d_in[0];     // [2048][4096] int32
  const int*   weight = (const int*)d_in[1];     // [11008][4096] int32 in {-1,0,1}
  const float* scale  = (const float*)d_in[2];   // [11008]
  const float* bias   = (const float*)d_in[3];   // [11008]
  float*       out    = (float*)d_out;           // [2048][11008] fp32

  const size_t needA = (size_t)BATCH * KDIM;     // 8 MB int8
  const size_t needB = (size_t)NDIM * KDIM;      // 44 MB int8

  char* A8 = (char*)d_ws;
  char* B8 = A8 + needA;
  const int nA4 = (int)(needA / 4);
  const int nB4 = (int)(needB / 4);
  convert_i32_i8<<<(nA4 + 255) / 256, 256, 0, stream>>>(input, (unsigned*)A8, nA4);
  convert_i32_i8<<<(nB4 + 255) / 256, 256, 0, stream>>>(weight, (unsigned*)B8, nB4);

  const dim3 grid((BATCH / BM) * (NDIM / BN));   // 16 * 43 = 688
  const dim3 block(256);
  ternary_gemm<<<grid, block, 0, stream>>>(A8, B8, scale, bias, out);
  (void)ws_size; (void)n_in; (void)in_sizes; (void)out_size;
}